// Round 3
// baseline (1108.082 us; speedup 1.0000x reference)
//
#include <hip/hip_runtime.h>
#include <stdint.h>

typedef __attribute__((ext_vector_type(8))) short short8;
typedef __attribute__((ext_vector_type(4))) float floatx4;

#define SEQ    2048
#define HID    4096
#define NHEAD  32
#define HDIMV  128
#define PROJN  12288

__device__ __forceinline__ unsigned short f2bf(float f) {
  union { float f; unsigned u; } v; v.f = f;
  unsigned r = (v.u + 0x7fffu + ((v.u >> 16) & 1u)) >> 16;
  return (unsigned short)r;
}

// -------------------- fp32 -> bf16 convert --------------------
__global__ __launch_bounds__(256) void cvt_kernel(const float* __restrict__ src,
                                                  unsigned short* __restrict__ dst) {
  long i = ((long)blockIdx.x * 256 + threadIdx.x) * 8;
  float4 a = *(const float4*)(src + i);
  float4 b = *(const float4*)(src + i + 4);
  short8 o;
  o[0] = (short)f2bf(a.x); o[1] = (short)f2bf(a.y);
  o[2] = (short)f2bf(a.z); o[3] = (short)f2bf(a.w);
  o[4] = (short)f2bf(b.x); o[5] = (short)f2bf(b.y);
  o[6] = (short)f2bf(b.z); o[7] = (short)f2bf(b.w);
  *(short8*)(dst + i) = o;
}

// -------------------- async 16B global->LDS --------------------
__device__ __forceinline__ void g2l16(const void* g, void* l) {
  __builtin_amdgcn_global_load_lds(
      (const __attribute__((address_space(1))) void*)g,
      (__attribute__((address_space(3))) void*)l, 16, 0, 0);
}

// Stage a 128x128 bf16 tile (row pitch `pitch`) into chunk-major LDS:
// elem (r,c) -> lds[((c>>3)*128 + r)*8 + (c&7)].
__device__ __forceinline__ void stage128(const unsigned short* g, long pitch,
                                         unsigned short* lds, int t) {
  const int sr = t & 127;
  const int skc = (t >> 7) & 1;
  const int wave = t >> 6;
  const unsigned short* gp = g + (long)sr * pitch + skc * 8;
  unsigned short* lp = lds + wave * 512;
#pragma unroll
  for (int k = 0; k < 8; k++) g2l16(gp + k * 16, lp + k * 2048);
}

// -------------------- NT GEMM: C[MxN] = A[MxK] * B[NxK]^T --------------------
// 128x128 tile, BK=64, 4 waves each 64x64 via 4x4 of 16x16x32 bf16 MFMA.
// 1-D grid, XCD swizzle: xcd = bid&7 selects n%8 so blocks sharing a B panel
// run time-local on one XCD (L2-hot staging). nbm fixed at 16 (M=2048).
template<int OUT_F32>
__global__ __launch_bounds__(256, 4) void gemm_nt(
    const unsigned short* __restrict__ A,
    const unsigned short* __restrict__ B,
    void* __restrict__ C, int M, int N, int K) {
  __shared__ __align__(16) unsigned short As[8192];  // 128 rows x 64 k, chunk-major
  __shared__ __align__(16) unsigned short Bs[8192];
  const int t = threadIdx.x;
  const int wave = t >> 6;
  const int lane = t & 63;
  const int bid = blockIdx.x;
  const int xcd = bid & 7;
  const int li = bid >> 3;
  const int m0 = (li & 15) * 128;
  const int n0 = ((li >> 4) * 8 + xcd) * 128;

  // staging: thread t covers chunks t + j*256 (j=0..3) per matrix
  const int srow = t & 127;
  const int skc = t >> 7;  // 0..1
  const unsigned short* ap = A + (long)(m0 + srow) * K + skc * 8;
  const unsigned short* bp = B + (long)(n0 + srow) * K + skc * 8;
  unsigned short* asl = As + wave * 512;
  unsigned short* bsl = Bs + wave * 512;

  const int mw = (wave >> 1) * 64;
  const int nw = (wave & 1) * 64;
  const int lq = lane & 15, lg = lane >> 4;

  floatx4 zero = {0.f, 0.f, 0.f, 0.f};
  floatx4 acc[4][4];
  for (int i = 0; i < 4; i++)
    for (int j = 0; j < 4; j++) acc[i][j] = zero;

  for (int k0 = 0; k0 < K; k0 += 64) {
    __syncthreads();
#pragma unroll
    for (int j = 0; j < 4; j++) g2l16(ap + k0 + j * 16, asl + j * 2048);
#pragma unroll
    for (int j = 0; j < 4; j++) g2l16(bp + k0 + j * 16, bsl + j * 2048);
    __syncthreads();
#pragma unroll
    for (int kk = 0; kk < 2; kk++) {
      const int ch = (kk * 4 + lg) * 1024;
      short8 af[4], bfr[4];
#pragma unroll
      for (int i = 0; i < 4; i++)
        af[i] = *(const short8*)(As + ch + (mw + i * 16 + lq) * 8);
#pragma unroll
      for (int j = 0; j < 4; j++)
        bfr[j] = *(const short8*)(Bs + ch + (nw + j * 16 + lq) * 8);
#pragma unroll
      for (int i = 0; i < 4; i++)
#pragma unroll
        for (int j = 0; j < 4; j++)
          acc[i][j] = __builtin_amdgcn_mfma_f32_16x16x32_bf16(af[i], bfr[j], acc[i][j], 0, 0, 0);
    }
  }

  const int row0 = m0 + mw + lg * 4;
  const int col0 = n0 + nw + lq;
  if (OUT_F32) {
    float* Cf = (float*)C;
#pragma unroll
    for (int i = 0; i < 4; i++)
#pragma unroll
      for (int j = 0; j < 4; j++)
#pragma unroll
        for (int r = 0; r < 4; r++)
          Cf[(long)(row0 + i * 16 + r) * N + col0 + j * 16] = acc[i][j][r];
  } else {
    unsigned short* Cb = (unsigned short*)C;
#pragma unroll
    for (int i = 0; i < 4; i++)
#pragma unroll
      for (int j = 0; j < 4; j++)
#pragma unroll
        for (int r = 0; r < 4; r++)
          Cb[(long)(row0 + i * 16 + r) * N + col0 + j * 16] = f2bf(acc[i][j][r]);
  }
}

// -------------------- V transpose: proj V-slice -> Vt[h][d][s] --------------------
__global__ __launch_bounds__(256) void vtrans_kernel(const unsigned short* __restrict__ proj,
                                                     unsigned short* __restrict__ Vt) {
  __shared__ unsigned short T[128 * 136];
  const int st = blockIdx.x, h = blockIdx.y, t = threadIdx.x;
  const unsigned short* src = proj + (long)(st * 128) * PROJN + 2 * HID + h * 128;
#pragma unroll
  for (int it = 0; it < 8; it++) {
    int idx = t * 8 + it * 2048;
    int r = idx >> 7, c = idx & 127;
    *(short8*)(T + r * 136 + c) = *(const short8*)(src + (long)r * PROJN + c);
  }
  __syncthreads();
#pragma unroll
  for (int pass = 0; pass < 4; pass++) {
    int d = (t >> 3) + pass * 32;
    int sc = t & 7;
    short8 lo, hi;
#pragma unroll
    for (int j = 0; j < 8; j++)  lo[j] = (short)T[(sc * 16 + j) * 136 + d];
#pragma unroll
    for (int j = 0; j < 8; j++)  hi[j] = (short)T[(sc * 16 + 8 + j) * 136 + d];
    unsigned short* dst = Vt + (long)(h * 128 + d) * 2048 + st * 128 + sc * 16;
    *(short8*)dst = lo;
    *(short8*)(dst + 8) = hi;
  }
}

// -------------------- causal flash attention (barrier-free kv loop) ---------------
// 512 blocks heavy-first: h = bx&31, qt = 15-(bx>>5). 4 waves; wave w owns Q rows
// w*32..+31 (wave-private). Q frags in regs; K/V B-frags loaded 16B direct from
// global; P via chunk-major LDS reusing Q staging buffer. One barrier total.
__global__ __launch_bounds__(256, 2) void attn_kernel(
    const unsigned short* __restrict__ proj,
    const unsigned short* __restrict__ Vt,
    unsigned short* __restrict__ ao) {
  __shared__ __align__(16) unsigned short Qs[16384];  // 32 KB; becomes P after init
  const int bx = blockIdx.x;
  const int h = bx & 31;
  const int qt = 15 - (bx >> 5);
  const int t = threadIdx.x, wave = t >> 6, lane = t & 63;
  const int lq = lane & 15, lg = lane >> 4;
  const int wOff = wave * 32;
  const float scale2 = 0.12751744154f;  // (1/sqrt(128)) * log2(e)

  // stage Q tile, pull wave-private frags to registers
  stage128(proj + (long)(qt * 128) * PROJN + h * 128, PROJN, Qs, t);
  __syncthreads();
  short8 qf[2][4];
#pragma unroll
  for (int i = 0; i < 2; i++)
#pragma unroll
    for (int kk = 0; kk < 4; kk++)
      qf[i][kk] = *(const short8*)(Qs + ((kk * 4 + lg) * 128 + wOff + i * 16 + lq) * 8);
  unsigned short* Ps = Qs;  // reuse: P rows are wave-private from here on

  float mraw[2][4], lsum[2][4];
  floatx4 zero = {0.f, 0.f, 0.f, 0.f};
  floatx4 o[2][8];
#pragma unroll
  for (int i = 0; i < 2; i++)
#pragma unroll
    for (int r = 0; r < 4; r++) { mraw[i][r] = -INFINITY; lsum[i][r] = 0.f; }
#pragma unroll
  for (int i = 0; i < 2; i++)
#pragma unroll
    for (int j = 0; j < 8; j++) o[i][j] = zero;

  const unsigned short* kb0 = proj + (long)lq * PROJN + HID + h * 128 + lg * 8;
  const unsigned short* vb0 = Vt + (long)(h * 128 + lq) * 2048 + lg * 8;

  for (int kv = 0; kv <= qt; kv++) {
    const bool diag = (kv == qt);
    const unsigned short* kb = kb0 + (long)(kv * 128) * PROJN;
    const unsigned short* vb = vb0 + kv * 128;

    // S = Q K^T : K B-frags straight from global (16B contiguous along d)
    floatx4 s[2][8];
#pragma unroll
    for (int i = 0; i < 2; i++)
#pragma unroll
      for (int j = 0; j < 8; j++) s[i][j] = zero;
#pragma unroll
    for (int kk = 0; kk < 4; kk++) {
      short8 bfr[8];
#pragma unroll
      for (int j = 0; j < 8; j++)
        bfr[j] = *(const short8*)(kb + (long)j * (16 * PROJN) + kk * 32);
#pragma unroll
      for (int i = 0; i < 2; i++)
#pragma unroll
        for (int j = 0; j < 8; j++)
          s[i][j] = __builtin_amdgcn_mfma_f32_16x16x32_bf16(qf[i][kk], bfr[j], s[i][j], 0, 0, 0);
    }

    // causal mask only on the diagonal tile
    if (diag) {
#pragma unroll
      for (int i = 0; i < 2; i++)
#pragma unroll
        for (int r = 0; r < 4; r++) {
          int qrow = qt * 128 + wOff + i * 16 + lg * 4 + r;
#pragma unroll
          for (int j = 0; j < 8; j++)
            if (kv * 128 + j * 16 + lq > qrow) s[i][j][r] = -INFINITY;
        }
    }

    // online softmax, exp2 domain, raw-domain running max
    float alpha_[2][4];
#pragma unroll
    for (int i = 0; i < 2; i++) {
#pragma unroll
      for (int r = 0; r < 4; r++) {
        float mx = s[i][0][r];
#pragma unroll
        for (int j = 1; j < 8; j++) mx = fmaxf(mx, s[i][j][r]);
#pragma unroll
        for (int d = 1; d < 16; d <<= 1) mx = fmaxf(mx, __shfl_xor(mx, d, 64));
        float mnew = fmaxf(mraw[i][r], mx);
        float al = exp2f((mraw[i][r] - mnew) * scale2);
        float c = mnew * scale2;
        float ps = 0.f;
#pragma unroll
        for (int j = 0; j < 8; j++) {
          float p = exp2f(fmaf(s[i][j][r], scale2, -c));
          s[i][j][r] = p;
          ps += p;
        }
#pragma unroll
        for (int d = 1; d < 16; d <<= 1) ps += __shfl_xor(ps, d, 64);
        lsum[i][r] = lsum[i][r] * al + ps;
        mraw[i][r] = mnew;
        alpha_[i][r] = al;
      }
    }
#pragma unroll
    for (int i = 0; i < 2; i++)
#pragma unroll
      for (int j = 0; j < 8; j++)
#pragma unroll
        for (int r = 0; r < 4; r++) o[i][j][r] *= alpha_[i][r];

    // P (C-layout regs) -> chunk-major LDS, wave-private rows, no barrier
#pragma unroll
    for (int i = 0; i < 2; i++)
#pragma unroll
      for (int r = 0; r < 4; r++) {
        int prow = wOff + i * 16 + lg * 4 + r;
#pragma unroll
        for (int j = 0; j < 8; j++)
          Ps[((j * 2 + (lq >> 3)) * 128 + prow) * 8 + (lq & 7)] = f2bf(s[i][j][r]);
      }

    // O += P V : A-frags from own P rows (LDS), B-frags 16B direct from Vt
#pragma unroll
    for (int kk = 0; kk < 4; kk++) {
      short8 pf[2], vf[8];
#pragma unroll
      for (int i = 0; i < 2; i++)
        pf[i] = *(const short8*)(Ps + ((kk * 4 + lg) * 128 + wOff + i * 16 + lq) * 8);
#pragma unroll
      for (int j = 0; j < 8; j++)
        vf[j] = *(const short8*)(vb + (long)j * (16 * 2048) + kk * 32);
#pragma unroll
      for (int i = 0; i < 2; i++)
#pragma unroll
        for (int j = 0; j < 8; j++)
          o[i][j] = __builtin_amdgcn_mfma_f32_16x16x32_bf16(pf[i], vf[j], o[i][j], 0, 0, 0);
    }
  }

  // epilogue: normalize, pack via wave-private P rows, coalesced 16B stores
#pragma unroll
  for (int i = 0; i < 2; i++) {
    float inv[4];
#pragma unroll
    for (int r = 0; r < 4; r++) inv[r] = 1.0f / lsum[i][r];
#pragma unroll
    for (int r = 0; r < 4; r++) {
      int prow = wOff + i * 16 + lg * 4 + r;
#pragma unroll
      for (int j = 0; j < 8; j++)
        Ps[((j * 2 + (lq >> 3)) * 128 + prow) * 8 + (lq & 7)] = f2bf(o[i][j][r] * inv[r]);
    }
  }
#pragma unroll
  for (int it = 0; it < 8; it++) {
    int row_loc = it * 4 + (lane >> 4);
    int cc = lane & 15;
    short8 v = *(const short8*)(Ps + (cc * 128 + wOff + row_loc) * 8);
    *(short8*)(ao + (long)(qt * 128 + wOff + row_loc) * HID + h * 128 + cc * 8) = v;
  }
}

// -------------------- launcher --------------------
extern "C" void kernel_launch(void* const* d_in, const int* in_sizes, int n_in,
                              void* d_out, int out_size, void* d_ws, size_t ws_size,
                              hipStream_t stream) {
  (void)in_sizes; (void)n_in; (void)out_size;
  const float* hs = (const float*)d_in[0];
  // d_in[1] = attention_mask: deterministic causal, applied analytically
  const float* wp = (const float*)d_in[2];
  const float* wo = (const float*)d_in[3];
  float* out = (float*)d_out;
  char* ws = (char*)d_ws;

  unsigned short* Xb   = (unsigned short*)(ws);                 // 2048*4096 bf16   (16 MiB)
  unsigned short* Wpb  = (unsigned short*)(ws + 16777216);      // 12288*4096 bf16  (96 MiB)
  unsigned short* Wob  = (unsigned short*)(ws + 117440512);     // 4096*4096 bf16   (32 MiB)
  unsigned short* proj = (unsigned short*)(ws + 150994944);     // 2048*12288 bf16  (48 MiB)
  unsigned short* ao   = (unsigned short*)(ws + 201326592);     // 2048*4096 bf16   (16 MiB)
  unsigned short* Vt   = Xb;                                    // reuse after gemm1
  if (ws_size < 218103808) return;

  cvt_kernel<<<8388608 / 2048, 256, 0, stream>>>(hs, Xb);
  cvt_kernel<<<50331648 / 2048, 256, 0, stream>>>(wp, Wpb);
  cvt_kernel<<<16777216 / 2048, 256, 0, stream>>>(wo, Wob);

  gemm_nt<0><<<1536, 256, 0, stream>>>(Xb, Wpb, (void*)proj, SEQ, PROJN, HID);
  vtrans_kernel<<<dim3(16, 32), 256, 0, stream>>>(proj, Vt);
  attn_kernel<<<512, 256, 0, stream>>>(proj, Vt, ao);
  gemm_nt<1><<<512, 256, 0, stream>>>(ao, Wob, (void*)out, SEQ, HID, HID);
}

// Round 4
// 966.077 us; speedup vs baseline: 1.1470x; 1.1470x over previous
//
#include <hip/hip_runtime.h>
#include <stdint.h>

typedef __attribute__((ext_vector_type(8))) short short8;
typedef __attribute__((ext_vector_type(4))) float floatx4;

#define SEQ    2048
#define HID    4096
#define NHEAD  32
#define HDIMV  128
#define PROJN  12288

__device__ __forceinline__ unsigned short f2bf(float f) {
  union { float f; unsigned u; } v; v.f = f;
  unsigned r = (v.u + 0x7fffu + ((v.u >> 16) & 1u)) >> 16;
  return (unsigned short)r;
}

// -------------------- async 16B global->LDS --------------------
__device__ __forceinline__ void g2l16(const void* g, void* l) {
  __builtin_amdgcn_global_load_lds(
      (const __attribute__((address_space(1))) void*)g,
      (__attribute__((address_space(3))) void*)l, 16, 0, 0);
}

// ---------- pack fp32 [R x K] row-major -> bf16 tile images ----------
// Tile (rp, kt) = 128 rows x 64 k, chunk-major: elem (r,c) at
// tile*8192 + ((c>>3)*128 + r)*8 + (c&7). One-time scattered read, coalesced write.
__global__ __launch_bounds__(256) void pack_fp32(const float* __restrict__ src,
                                                 unsigned short* __restrict__ dst, int K) {
  const int rp = blockIdx.x, kt = blockIdx.y, t = threadIdx.x;
  const long tb = ((long)rp * gridDim.y + kt) * 8192;
#pragma unroll
  for (int j = 0; j < 4; j++) {
    int ch = t + j * 256;
    int r = ch & 127, cc = ch >> 7;
    const float* s = src + (long)(rp * 128 + r) * K + kt * 64 + cc * 8;
    float4 a = *(const float4*)s;
    float4 b = *(const float4*)(s + 4);
    short8 o;
    o[0] = (short)f2bf(a.x); o[1] = (short)f2bf(a.y);
    o[2] = (short)f2bf(a.z); o[3] = (short)f2bf(a.w);
    o[4] = (short)f2bf(b.x); o[5] = (short)f2bf(b.y);
    o[6] = (short)f2bf(b.z); o[7] = (short)f2bf(b.w);
    *(short8*)(dst + tb + ch * 8) = o;
  }
}

// ---------- pack Q,K slices of proj -> per-(h,tile) 128x128 chunk-major ----------
// Tile (h, st): elem (s_local, d) at ((h*16+st)*16384) + ((d>>3)*128 + s_local)*8 + (d&7)
__global__ __launch_bounds__(256) void pack_qk(const unsigned short* __restrict__ proj,
                                               unsigned short* __restrict__ dstQ,
                                               unsigned short* __restrict__ dstK) {
  const int st = blockIdx.x, h = blockIdx.y, t = threadIdx.x;
  const long tb = ((long)(h * 16 + st)) * 16384;
#pragma unroll
  for (int j = 0; j < 8; j++) {
    int ch = t + j * 256;            // 0..2047
    int r = ch & 127, cc = ch >> 7;  // cc 0..15
    long so = (long)(st * 128 + r) * PROJN + h * 128 + cc * 8;
    *(short8*)(dstQ + tb + ch * 8) = *(const short8*)(proj + so);
    *(short8*)(dstK + tb + ch * 8) = *(const short8*)(proj + so + HID);
  }
}

// ---------- pack V^T: proj V-slice -> per-(h,tile) chunk-major with row=d, k=s ----------
// elem (d, s_local) at ((h*16+st)*16384) + ((s_local>>3)*128 + d)*8 + (s_local&7)
__global__ __launch_bounds__(256) void pack_v(const unsigned short* __restrict__ proj,
                                              unsigned short* __restrict__ Vf) {
  __shared__ unsigned short T[128 * 136];
  const int st = blockIdx.x, h = blockIdx.y, t = threadIdx.x;
  const long tb = ((long)(h * 16 + st)) * 16384;
  const unsigned short* src = proj + (long)(st * 128) * PROJN + 2 * HID + h * 128;
#pragma unroll
  for (int it = 0; it < 8; it++) {
    int idx = t * 8 + it * 2048;
    int r = idx >> 7, c = idx & 127;
    *(short8*)(T + r * 136 + c) = *(const short8*)(src + (long)r * PROJN + c);
  }
  __syncthreads();
#pragma unroll
  for (int pass = 0; pass < 4; pass++) {
    int d = (t >> 3) + pass * 32;
    int sc = t & 7;  // s-group: s = sc*16 .. +16
    short8 lo, hi;
#pragma unroll
    for (int j = 0; j < 8; j++) lo[j] = (short)T[(sc * 16 + j) * 136 + d];
#pragma unroll
    for (int j = 0; j < 8; j++) hi[j] = (short)T[(sc * 16 + 8 + j) * 136 + d];
    *(short8*)(Vf + tb + ((sc * 2) * 128 + d) * 8) = lo;
    *(short8*)(Vf + tb + ((sc * 2 + 1) * 128 + d) * 8) = hi;
  }
}

// -------------------- NT GEMM on packed tiles --------------------
// A: tiles (mi, kt) 128x64 chunk-major, m-major (base = (mi*KT+kt)*8192); B same by n.
// BK=64, 4 waves x (4x4 of 16x16x32). Staging = coalesced global_load_lds.
template<int OUT_F32>
__global__ __launch_bounds__(256, 4) void gemm_pk(
    const unsigned short* __restrict__ Ap,
    const unsigned short* __restrict__ Bp,
    void* __restrict__ C, int N, int K) {
  __shared__ __align__(16) unsigned short As[8192];
  __shared__ __align__(16) unsigned short Bs[8192];
  const int t = threadIdx.x;
  const int wave = t >> 6, lane = t & 63;
  const int bid = blockIdx.x;
  const int xcd = bid & 7;
  const int li = bid >> 3;
  const int mi = li & 15;                  // M = 2048 -> 16 m-tiles
  const int ni = (li >> 4) * 8 + xcd;      // XCD-local n-panel sharing
  const int KT = K >> 6;
  const unsigned short* at = Ap + (long)mi * KT * 8192 + t * 8;
  const unsigned short* bt = Bp + (long)ni * KT * 8192 + t * 8;
  unsigned short* asl = As + wave * 512;
  unsigned short* bsl = Bs + wave * 512;

  const int mw = (wave >> 1) * 64;
  const int nw = (wave & 1) * 64;
  const int lq = lane & 15, lg = lane >> 4;

  floatx4 zero = {0.f, 0.f, 0.f, 0.f};
  floatx4 acc[4][4];
  for (int i = 0; i < 4; i++)
    for (int j = 0; j < 4; j++) acc[i][j] = zero;

  for (int kt = 0; kt < KT; kt++) {
    __syncthreads();
    const unsigned short* ak = at + (long)kt * 8192;
    const unsigned short* bk = bt + (long)kt * 8192;
#pragma unroll
    for (int j = 0; j < 4; j++) g2l16(ak + j * 2048, asl + j * 2048);
#pragma unroll
    for (int j = 0; j < 4; j++) g2l16(bk + j * 2048, bsl + j * 2048);
    __syncthreads();
#pragma unroll
    for (int kk = 0; kk < 2; kk++) {
      const int ch = (kk * 4 + lg) * 1024;
      short8 af[4], bfr[4];
#pragma unroll
      for (int i = 0; i < 4; i++)
        af[i] = *(const short8*)(As + ch + (mw + i * 16 + lq) * 8);
#pragma unroll
      for (int j = 0; j < 4; j++)
        bfr[j] = *(const short8*)(Bs + ch + (nw + j * 16 + lq) * 8);
#pragma unroll
      for (int i = 0; i < 4; i++)
#pragma unroll
        for (int j = 0; j < 4; j++)
          acc[i][j] = __builtin_amdgcn_mfma_f32_16x16x32_bf16(af[i], bfr[j], acc[i][j], 0, 0, 0);
    }
  }

  const int row0 = mi * 128 + mw + lg * 4;
  const int col0 = ni * 128 + nw + lq;
  if (OUT_F32) {
    float* Cf = (float*)C;
#pragma unroll
    for (int i = 0; i < 4; i++)
#pragma unroll
      for (int j = 0; j < 4; j++)
#pragma unroll
        for (int r = 0; r < 4; r++)
          Cf[(long)(row0 + i * 16 + r) * N + col0 + j * 16] = acc[i][j][r];
  } else {
    unsigned short* Cb = (unsigned short*)C;
#pragma unroll
    for (int i = 0; i < 4; i++)
#pragma unroll
      for (int j = 0; j < 4; j++)
#pragma unroll
        for (int r = 0; r < 4; r++)
          Cb[(long)(row0 + i * 16 + r) * N + col0 + j * 16] = f2bf(acc[i][j][r]);
  }
}

// -------------------- causal flash attention (all frag loads coalesced) -----------
// 512 blocks heavy-first: h = bx&31, qt = 15-(bx>>5). 4 waves, wave-private rows,
// ZERO barriers. Q/K/V read from packed per-(h,tile) images; P via 32KB LDS.
// Output written directly in gemm2 A-pack format (tiles (qt, kt), kt = k/64).
__global__ __launch_bounds__(256, 2) void attn_kernel(
    const unsigned short* __restrict__ Qf,
    const unsigned short* __restrict__ Kf,
    const unsigned short* __restrict__ Vf,
    unsigned short* __restrict__ aop) {
  __shared__ __align__(16) unsigned short Ps[16384];
  const int bx = blockIdx.x;
  const int h = bx & 31;
  const int qt = 15 - (bx >> 5);
  const int t = threadIdx.x, wave = t >> 6, lane = t & 63;
  const int lq = lane & 15, lg = lane >> 4;
  const int wOff = wave * 32;
  const float scale2 = 0.12751744154f;  // (1/sqrt(128)) * log2(e)

  // Q fragments: coalesced global reads from packed image, kept in regs
  const unsigned short* qb = Qf + ((long)(h * 16 + qt)) * 16384;
  short8 qf[2][4];
#pragma unroll
  for (int i = 0; i < 2; i++)
#pragma unroll
    for (int kk = 0; kk < 4; kk++)
      qf[i][kk] = *(const short8*)(qb + ((kk * 4 + lg) * 128 + wOff + i * 16 + lq) * 8);

  float mraw[2][4], lsum[2][4];
  floatx4 zero = {0.f, 0.f, 0.f, 0.f};
  floatx4 o[2][8];
#pragma unroll
  for (int i = 0; i < 2; i++)
#pragma unroll
    for (int r = 0; r < 4; r++) { mraw[i][r] = -INFINITY; lsum[i][r] = 0.f; }
#pragma unroll
  for (int i = 0; i < 2; i++)
#pragma unroll
    for (int j = 0; j < 8; j++) o[i][j] = zero;

  for (int kv = 0; kv <= qt; kv++) {
    const bool diag = (kv == qt);
    const unsigned short* kb = Kf + ((long)(h * 16 + kv)) * 16384;
    const unsigned short* vb = Vf + ((long)(h * 16 + kv)) * 16384;

    // S = Q K^T (B-frags coalesced from packed K image)
    floatx4 s[2][8];
#pragma unroll
    for (int i = 0; i < 2; i++)
#pragma unroll
      for (int j = 0; j < 8; j++) s[i][j] = zero;
#pragma unroll
    for (int kk = 0; kk < 4; kk++) {
      short8 bfr[8];
#pragma unroll
      for (int j = 0; j < 8; j++)
        bfr[j] = *(const short8*)(kb + ((kk * 4 + lg) * 128 + j * 16 + lq) * 8);
#pragma unroll
      for (int i = 0; i < 2; i++)
#pragma unroll
        for (int j = 0; j < 8; j++)
          s[i][j] = __builtin_amdgcn_mfma_f32_16x16x32_bf16(qf[i][kk], bfr[j], s[i][j], 0, 0, 0);
    }

    if (diag) {
#pragma unroll
      for (int i = 0; i < 2; i++)
#pragma unroll
        for (int r = 0; r < 4; r++) {
          int qrow = qt * 128 + wOff + i * 16 + lg * 4 + r;
#pragma unroll
          for (int j = 0; j < 8; j++)
            if (kv * 128 + j * 16 + lq > qrow) s[i][j][r] = -INFINITY;
        }
    }

    // online softmax (exp2 domain, raw-domain running max)
    float alpha_[2][4];
#pragma unroll
    for (int i = 0; i < 2; i++) {
#pragma unroll
      for (int r = 0; r < 4; r++) {
        float mx = s[i][0][r];
#pragma unroll
        for (int j = 1; j < 8; j++) mx = fmaxf(mx, s[i][j][r]);
#pragma unroll
        for (int d = 1; d < 16; d <<= 1) mx = fmaxf(mx, __shfl_xor(mx, d, 64));
        float mnew = fmaxf(mraw[i][r], mx);
        float al = exp2f((mraw[i][r] - mnew) * scale2);
        float c = mnew * scale2;
        float ps = 0.f;
#pragma unroll
        for (int j = 0; j < 8; j++) {
          float p = exp2f(fmaf(s[i][j][r], scale2, -c));
          s[i][j][r] = p;
          ps += p;
        }
#pragma unroll
        for (int d = 1; d < 16; d <<= 1) ps += __shfl_xor(ps, d, 64);
        lsum[i][r] = lsum[i][r] * al + ps;
        mraw[i][r] = mnew;
        alpha_[i][r] = al;
      }
    }
#pragma unroll
    for (int i = 0; i < 2; i++)
#pragma unroll
      for (int j = 0; j < 8; j++)
#pragma unroll
        for (int r = 0; r < 4; r++) o[i][j][r] *= alpha_[i][r];

    // P (C-layout regs) -> chunk-major LDS, wave-private rows, no barrier
#pragma unroll
    for (int i = 0; i < 2; i++)
#pragma unroll
      for (int r = 0; r < 4; r++) {
        int prow = wOff + i * 16 + lg * 4 + r;
#pragma unroll
        for (int j = 0; j < 8; j++)
          Ps[((j * 2 + (lq >> 3)) * 128 + prow) * 8 + (lq & 7)] = f2bf(s[i][j][r]);
      }

    // O += P V (A-frags from own P rows in LDS, B-frags coalesced from packed V^T)
#pragma unroll
    for (int kk = 0; kk < 4; kk++) {
      short8 pf[2], vf[8];
#pragma unroll
      for (int i = 0; i < 2; i++)
        pf[i] = *(const short8*)(Ps + ((kk * 4 + lg) * 128 + wOff + i * 16 + lq) * 8);
#pragma unroll
      for (int j = 0; j < 8; j++)
        vf[j] = *(const short8*)(vb + ((kk * 4 + lg) * 128 + j * 16 + lq) * 8);
#pragma unroll
      for (int i = 0; i < 2; i++)
#pragma unroll
        for (int j = 0; j < 8; j++)
          o[i][j] = __builtin_amdgcn_mfma_f32_16x16x32_bf16(pf[i], vf[j], o[i][j], 0, 0, 0);
    }
  }

  // epilogue: normalize, pack via wave-private P rows, write gemm2 A-pack tiles
#pragma unroll
  for (int i = 0; i < 2; i++) {
    float inv[4];
#pragma unroll
    for (int r = 0; r < 4; r++) inv[r] = 1.0f / lsum[i][r];
#pragma unroll
    for (int r = 0; r < 4; r++) {
      int prow = wOff + i * 16 + lg * 4 + r;
#pragma unroll
      for (int j = 0; j < 8; j++)
        Ps[((j * 2 + (lq >> 3)) * 128 + prow) * 8 + (lq & 7)] = f2bf(o[i][j][r] * inv[r]);
    }
  }
  // A-pack: tile (mi=qt, kt = h*2 + (cc>>3)), chunk = (cc&7)*128 + row, KT=64
#pragma unroll
  for (int it = 0; it < 8; it++) {
    int row_loc = it * 4 + (lane >> 4);
    int cc = lane & 15;
    short8 v = *(const short8*)(Ps + (cc * 128 + wOff + row_loc) * 8);
    long tb = ((long)qt * 64 + h * 2 + (cc >> 3)) * 8192;
    *(short8*)(aop + tb + ((cc & 7) * 128 + wOff + row_loc) * 8) = v;
  }
}

// -------------------- launcher --------------------
extern "C" void kernel_launch(void* const* d_in, const int* in_sizes, int n_in,
                              void* d_out, int out_size, void* d_ws, size_t ws_size,
                              hipStream_t stream) {
  (void)in_sizes; (void)n_in; (void)out_size;
  const float* hs = (const float*)d_in[0];
  // d_in[1] = attention_mask: deterministic causal, applied analytically
  const float* wp = (const float*)d_in[2];
  const float* wo = (const float*)d_in[3];
  float* out = (float*)d_out;
  char* ws = (char*)d_ws;

  // ws layout (bytes), with dead-region reuse:
  unsigned short* Ap1  = (unsigned short*)(ws);                 // X pack    16 MiB  @0
  unsigned short* Bp1  = (unsigned short*)(ws + 16777216);      // Wp pack   96 MiB  @16M
  unsigned short* Bp2  = (unsigned short*)(ws + 117440512);     // Wo pack   32 MiB  @112M
  unsigned short* proj = (unsigned short*)(ws + 150994944);     // proj      48 MiB  @144M
  unsigned short* aop  = (unsigned short*)(ws + 201326592);     // ao pack   16 MiB  @192M
  unsigned short* Qf   = (unsigned short*)(ws);                 // reuse Ap1 (dead after gemm1)
  unsigned short* Kf   = (unsigned short*)(ws + 16777216);      // reuse Bp1 head
  unsigned short* Vf   = (unsigned short*)(ws + 33554432);      // reuse Bp1 +16M
  if (ws_size < 218103808) return;  // need ~208 MiB

  pack_fp32<<<dim3(16, 64), 256, 0, stream>>>(hs, Ap1, HID);
  pack_fp32<<<dim3(96, 64), 256, 0, stream>>>(wp, Bp1, HID);
  pack_fp32<<<dim3(32, 64), 256, 0, stream>>>(wo, Bp2, HID);

  gemm_pk<0><<<1536, 256, 0, stream>>>(Ap1, Bp1, (void*)proj, PROJN, HID);

  pack_qk<<<dim3(16, 32), 256, 0, stream>>>(proj, Qf, Kf);
  pack_v<<<dim3(16, 32), 256, 0, stream>>>(proj, Vf);

  attn_kernel<<<512, 256, 0, stream>>>(Qf, Kf, Vf, aop);

  gemm_pk<1><<<512, 256, 0, stream>>>(aop, Bp2, (void*)out, HID, HID);
}

// Round 5
// 785.749 us; speedup vs baseline: 1.4102x; 1.2295x over previous
//
#include <hip/hip_runtime.h>
#include <stdint.h>

typedef __attribute__((ext_vector_type(8))) short short8;
typedef __attribute__((ext_vector_type(4))) float floatx4;

#define SEQ    2048
#define HID    4096
#define NHEAD  32
#define HDIMV  128
#define PROJN  12288

__device__ __forceinline__ unsigned short f2bf(float f) {
  union { float f; unsigned u; } v; v.f = f;
  unsigned r = (v.u + 0x7fffu + ((v.u >> 16) & 1u)) >> 16;
  return (unsigned short)r;
}

// -------------------- async 16B global->LDS --------------------
__device__ __forceinline__ void g2l16(const void* g, void* l) {
  __builtin_amdgcn_global_load_lds(
      (const __attribute__((address_space(1))) void*)g,
      (__attribute__((address_space(3))) void*)l, 16, 0, 0);
}

// ---------- pack fp32 [R x K] row-major -> bf16 tile images ----------
// Tile (rp, kt) = 128 rows x 64 k, chunk-major: elem (r,c) at
// tile*8192 + ((c>>3)*128 + r)*8 + (c&7). Rows < scale_rows get multiplied by
// scale (used to fold the softmax 1/sqrt(d)*log2(e) into w_pack's Q rows).
__global__ __launch_bounds__(256) void pack_fp32(const float* __restrict__ src,
                                                 unsigned short* __restrict__ dst, int K,
                                                 int scale_rows, float scale) {
  const int rp = blockIdx.x, kt = blockIdx.y, t = threadIdx.x;
  const long tb = ((long)rp * gridDim.y + kt) * 8192;
#pragma unroll
  for (int j = 0; j < 4; j++) {
    int ch = t + j * 256;
    int r = ch & 127, cc = ch >> 7;
    float sc = (rp * 128 + r < scale_rows) ? scale : 1.0f;
    const float* s = src + (long)(rp * 128 + r) * K + kt * 64 + cc * 8;
    float4 a = *(const float4*)s;
    float4 b = *(const float4*)(s + 4);
    short8 o;
    o[0] = (short)f2bf(a.x * sc); o[1] = (short)f2bf(a.y * sc);
    o[2] = (short)f2bf(a.z * sc); o[3] = (short)f2bf(a.w * sc);
    o[4] = (short)f2bf(b.x * sc); o[5] = (short)f2bf(b.y * sc);
    o[6] = (short)f2bf(b.z * sc); o[7] = (short)f2bf(b.w * sc);
    *(short8*)(dst + tb + ch * 8) = o;
  }
}

// ---------- pack Q,K slices of proj -> per-(h,tile) 128x128 chunk-major ----------
__global__ __launch_bounds__(256) void pack_qk(const unsigned short* __restrict__ proj,
                                               unsigned short* __restrict__ dstQ,
                                               unsigned short* __restrict__ dstK) {
  const int st = blockIdx.x, h = blockIdx.y, t = threadIdx.x;
  const long tb = ((long)(h * 16 + st)) * 16384;
#pragma unroll
  for (int j = 0; j < 8; j++) {
    int ch = t + j * 256;
    int r = ch & 127, cc = ch >> 7;
    long so = (long)(st * 128 + r) * PROJN + h * 128 + cc * 8;
    *(short8*)(dstQ + tb + ch * 8) = *(const short8*)(proj + so);
    *(short8*)(dstK + tb + ch * 8) = *(const short8*)(proj + so + HID);
  }
}

// ---------- pack V^T: proj V-slice -> per-(h,tile) chunk-major with row=d, k=s ----------
__global__ __launch_bounds__(256) void pack_v(const unsigned short* __restrict__ proj,
                                              unsigned short* __restrict__ Vf) {
  __shared__ unsigned short T[128 * 136];
  const int st = blockIdx.x, h = blockIdx.y, t = threadIdx.x;
  const long tb = ((long)(h * 16 + st)) * 16384;
  const unsigned short* src = proj + (long)(st * 128) * PROJN + 2 * HID + h * 128;
#pragma unroll
  for (int it = 0; it < 8; it++) {
    int idx = t * 8 + it * 2048;
    int r = idx >> 7, c = idx & 127;
    *(short8*)(T + r * 136 + c) = *(const short8*)(src + (long)r * PROJN + c);
  }
  __syncthreads();
#pragma unroll
  for (int pass = 0; pass < 4; pass++) {
    int d = (t >> 3) + pass * 32;
    int sc = t & 7;
    short8 lo, hi;
#pragma unroll
    for (int j = 0; j < 8; j++) lo[j] = (short)T[(sc * 16 + j) * 136 + d];
#pragma unroll
    for (int j = 0; j < 8; j++) hi[j] = (short)T[(sc * 16 + 8 + j) * 136 + d];
    *(short8*)(Vf + tb + ((sc * 2) * 128 + d) * 8) = lo;
    *(short8*)(Vf + tb + ((sc * 2 + 1) * 128 + d) * 8) = hi;
  }
}

// -------------------- NT GEMM on packed tiles --------------------
template<int OUT_F32>
__global__ __launch_bounds__(256, 4) void gemm_pk(
    const unsigned short* __restrict__ Ap,
    const unsigned short* __restrict__ Bp,
    void* __restrict__ C, int N, int K) {
  __shared__ __align__(16) unsigned short As[8192];
  __shared__ __align__(16) unsigned short Bs[8192];
  const int t = threadIdx.x;
  const int wave = t >> 6, lane = t & 63;
  const int bid = blockIdx.x;
  const int xcd = bid & 7;
  const int li = bid >> 3;
  const int mi = li & 15;
  const int ni = (li >> 4) * 8 + xcd;
  const int KT = K >> 6;
  const unsigned short* at = Ap + (long)mi * KT * 8192 + t * 8;
  const unsigned short* bt = Bp + (long)ni * KT * 8192 + t * 8;
  unsigned short* asl = As + wave * 512;
  unsigned short* bsl = Bs + wave * 512;

  const int mw = (wave >> 1) * 64;
  const int nw = (wave & 1) * 64;
  const int lq = lane & 15, lg = lane >> 4;

  floatx4 zero = {0.f, 0.f, 0.f, 0.f};
  floatx4 acc[4][4];
  for (int i = 0; i < 4; i++)
    for (int j = 0; j < 4; j++) acc[i][j] = zero;

  for (int kt = 0; kt < KT; kt++) {
    __syncthreads();
    const unsigned short* ak = at + (long)kt * 8192;
    const unsigned short* bk = bt + (long)kt * 8192;
#pragma unroll
    for (int j = 0; j < 4; j++) g2l16(ak + j * 2048, asl + j * 2048);
#pragma unroll
    for (int j = 0; j < 4; j++) g2l16(bk + j * 2048, bsl + j * 2048);
    __syncthreads();
#pragma unroll
    for (int kk = 0; kk < 2; kk++) {
      const int ch = (kk * 4 + lg) * 1024;
      short8 af[4], bfr[4];
#pragma unroll
      for (int i = 0; i < 4; i++)
        af[i] = *(const short8*)(As + ch + (mw + i * 16 + lq) * 8);
#pragma unroll
      for (int j = 0; j < 4; j++)
        bfr[j] = *(const short8*)(Bs + ch + (nw + j * 16 + lq) * 8);
#pragma unroll
      for (int i = 0; i < 4; i++)
#pragma unroll
        for (int j = 0; j < 4; j++)
          acc[i][j] = __builtin_amdgcn_mfma_f32_16x16x32_bf16(af[i], bfr[j], acc[i][j], 0, 0, 0);
    }
  }

  const int row0 = mi * 128 + mw + lg * 4;
  const int col0 = ni * 128 + nw + lq;
  if (OUT_F32) {
    float* Cf = (float*)C;
#pragma unroll
    for (int i = 0; i < 4; i++)
#pragma unroll
      for (int j = 0; j < 4; j++)
#pragma unroll
        for (int r = 0; r < 4; r++)
          Cf[(long)(row0 + i * 16 + r) * N + col0 + j * 16] = acc[i][j][r];
  } else {
    unsigned short* Cb = (unsigned short*)C;
#pragma unroll
    for (int i = 0; i < 4; i++)
#pragma unroll
      for (int j = 0; j < 4; j++)
#pragma unroll
        for (int r = 0; r < 4; r++)
          Cb[(long)(row0 + i * 16 + r) * N + col0 + j * 16] = f2bf(acc[i][j][r]);
  }
}

// stage one contiguous 32KB packed tile into LDS (wave-cooperative, coalesced)
__device__ __forceinline__ void stage_tile(const unsigned short* g, unsigned short* lds,
                                           int wave, int lane) {
  const unsigned short* gp = g + wave * 4096 + lane * 8;
  unsigned short* lp = lds + wave * 4096;
#pragma unroll
  for (int j = 0; j < 8; j++) g2l16(gp + j * 512, lp + j * 512);
}

// -------------------- causal flash attention --------------------
// 512 blocks heavy-first: h = bx&31, qt = 15-(bx>>5). 4 waves, 32 q-rows each.
// K/V double-buffered in LDS (one barrier per kv iter, prefetch overlaps compute).
// Q frags in regs; P round-trip via wave-private 32KB LDS. Q pre-scaled (log2 dom).
__global__ __launch_bounds__(256, 1) void attn_kernel(
    const unsigned short* __restrict__ Qf,
    const unsigned short* __restrict__ Kf,
    const unsigned short* __restrict__ Vf,
    unsigned short* __restrict__ aop) {
  __shared__ __align__(16) unsigned short Ks[2][16384];
  __shared__ __align__(16) unsigned short Vs[2][16384];
  __shared__ __align__(16) unsigned short Ps[16384];
  const int bx = blockIdx.x;
  const int h = bx & 31;
  const int qt = 15 - (bx >> 5);
  const int t = threadIdx.x, wave = t >> 6, lane = t & 63;
  const int lq = lane & 15, lg = lane >> 4;
  const int wOff = wave * 32;

  // Q fragments: coalesced global reads from packed image (Q pre-scaled)
  const unsigned short* qb = Qf + ((long)(h * 16 + qt)) * 16384;
  short8 qf[2][4];
#pragma unroll
  for (int i = 0; i < 2; i++)
#pragma unroll
    for (int kk = 0; kk < 4; kk++)
      qf[i][kk] = *(const short8*)(qb + ((kk * 4 + lg) * 128 + wOff + i * 16 + lq) * 8);

  float mraw[2][4], lsum[2][4];
  floatx4 zero = {0.f, 0.f, 0.f, 0.f};
  floatx4 o[2][8];
#pragma unroll
  for (int i = 0; i < 2; i++)
#pragma unroll
    for (int r = 0; r < 4; r++) { mraw[i][r] = -INFINITY; lsum[i][r] = 0.f; }
#pragma unroll
  for (int i = 0; i < 2; i++)
#pragma unroll
    for (int j = 0; j < 8; j++) o[i][j] = zero;

  const unsigned short* kb0 = Kf + ((long)h * 16) * 16384;
  const unsigned short* vb0 = Vf + ((long)h * 16) * 16384;
  stage_tile(kb0, Ks[0], wave, lane);
  stage_tile(vb0, Vs[0], wave, lane);

  for (int kv = 0; kv <= qt; kv++) {
    const int cur = kv & 1;
    const bool diag = (kv == qt);
    __syncthreads();  // cur buffers staged; prev-iter LDS reads done
    if (!diag) {
      stage_tile(kb0 + (long)(kv + 1) * 16384, Ks[1 - cur], wave, lane);
      stage_tile(vb0 + (long)(kv + 1) * 16384, Vs[1 - cur], wave, lane);
    }

    // S = Q K^T (already in log2 domain via pre-scaled Q)
    floatx4 s[2][8];
#pragma unroll
    for (int i = 0; i < 2; i++)
#pragma unroll
      for (int j = 0; j < 8; j++) s[i][j] = zero;
#pragma unroll
    for (int kk = 0; kk < 4; kk++) {
      short8 bfr[8];
#pragma unroll
      for (int j = 0; j < 8; j++)
        bfr[j] = *(const short8*)(&Ks[cur][((kk * 4 + lg) * 128 + j * 16 + lq) * 8]);
#pragma unroll
      for (int i = 0; i < 2; i++)
#pragma unroll
        for (int j = 0; j < 8; j++)
          s[i][j] = __builtin_amdgcn_mfma_f32_16x16x32_bf16(qf[i][kk], bfr[j], s[i][j], 0, 0, 0);
    }

    if (diag) {
#pragma unroll
      for (int i = 0; i < 2; i++)
#pragma unroll
        for (int r = 0; r < 4; r++) {
          int qrow = qt * 128 + wOff + i * 16 + lg * 4 + r;
#pragma unroll
          for (int j = 0; j < 8; j++)
            if (kv * 128 + j * 16 + lq > qrow) s[i][j][r] = -INFINITY;
        }
    }

    // online softmax (log2 domain; rows lane-local, reduce over 16 col-lanes)
    float alpha_[2][4];
#pragma unroll
    for (int i = 0; i < 2; i++) {
#pragma unroll
      for (int r = 0; r < 4; r++) {
        float mx = s[i][0][r];
#pragma unroll
        for (int j = 1; j < 8; j++) mx = fmaxf(mx, s[i][j][r]);
#pragma unroll
        for (int d = 1; d < 16; d <<= 1) mx = fmaxf(mx, __shfl_xor(mx, d, 64));
        float mnew = fmaxf(mraw[i][r], mx);
        float al = exp2f(mraw[i][r] - mnew);
        float ps = 0.f;
#pragma unroll
        for (int j = 0; j < 8; j++) {
          float p = exp2f(s[i][j][r] - mnew);
          s[i][j][r] = p;
          ps += p;
        }
#pragma unroll
        for (int d = 1; d < 16; d <<= 1) ps += __shfl_xor(ps, d, 64);
        lsum[i][r] = lsum[i][r] * al + ps;
        mraw[i][r] = mnew;
        alpha_[i][r] = al;
      }
    }
#pragma unroll
    for (int i = 0; i < 2; i++)
#pragma unroll
      for (int j = 0; j < 8; j++)
#pragma unroll
        for (int r = 0; r < 4; r++) o[i][j][r] *= alpha_[i][r];

    // P (C-layout regs) -> chunk-major LDS, wave-private rows, no barrier
#pragma unroll
    for (int i = 0; i < 2; i++)
#pragma unroll
      for (int r = 0; r < 4; r++) {
        int prow = wOff + i * 16 + lg * 4 + r;
#pragma unroll
        for (int j = 0; j < 8; j++)
          Ps[((j * 2 + (lq >> 3)) * 128 + prow) * 8 + (lq & 7)] = f2bf(s[i][j][r]);
      }

    // O += P V (A-frags from own P rows, B-frags from Vs tile in LDS)
#pragma unroll
    for (int kk = 0; kk < 4; kk++) {
      short8 pf[2], vf[8];
#pragma unroll
      for (int i = 0; i < 2; i++)
        pf[i] = *(const short8*)(Ps + ((kk * 4 + lg) * 128 + wOff + i * 16 + lq) * 8);
#pragma unroll
      for (int j = 0; j < 8; j++)
        vf[j] = *(const short8*)(&Vs[cur][((kk * 4 + lg) * 128 + j * 16 + lq) * 8]);
#pragma unroll
      for (int i = 0; i < 2; i++)
#pragma unroll
        for (int j = 0; j < 8; j++)
          o[i][j] = __builtin_amdgcn_mfma_f32_16x16x32_bf16(pf[i], vf[j], o[i][j], 0, 0, 0);
    }
  }

  // epilogue: normalize, pack via wave-private P rows, write gemm2 A-pack tiles
#pragma unroll
  for (int i = 0; i < 2; i++) {
    float inv[4];
#pragma unroll
    for (int r = 0; r < 4; r++) inv[r] = 1.0f / lsum[i][r];
#pragma unroll
    for (int r = 0; r < 4; r++) {
      int prow = wOff + i * 16 + lg * 4 + r;
#pragma unroll
      for (int j = 0; j < 8; j++)
        Ps[((j * 2 + (lq >> 3)) * 128 + prow) * 8 + (lq & 7)] = f2bf(o[i][j][r] * inv[r]);
    }
  }
#pragma unroll
  for (int it = 0; it < 8; it++) {
    int row_loc = it * 4 + (lane >> 4);
    int cc = lane & 15;
    short8 v = *(const short8*)(Ps + (cc * 128 + wOff + row_loc) * 8);
    long tb = ((long)qt * 64 + h * 2 + (cc >> 3)) * 8192;
    *(short8*)(aop + tb + ((cc & 7) * 128 + wOff + row_loc) * 8) = v;
  }
}

// -------------------- launcher --------------------
extern "C" void kernel_launch(void* const* d_in, const int* in_sizes, int n_in,
                              void* d_out, int out_size, void* d_ws, size_t ws_size,
                              hipStream_t stream) {
  (void)in_sizes; (void)n_in; (void)out_size;
  const float* hs = (const float*)d_in[0];
  // d_in[1] = attention_mask: deterministic causal, applied analytically
  const float* wp = (const float*)d_in[2];
  const float* wo = (const float*)d_in[3];
  float* out = (float*)d_out;
  char* ws = (char*)d_ws;

  unsigned short* Ap1  = (unsigned short*)(ws);                 // X pack    16 MiB  @0
  unsigned short* Bp1  = (unsigned short*)(ws + 16777216);      // Wp pack   96 MiB  @16M
  unsigned short* Bp2  = (unsigned short*)(ws + 117440512);     // Wo pack   32 MiB  @112M
  unsigned short* proj = (unsigned short*)(ws + 150994944);     // proj      48 MiB  @144M
  unsigned short* aop  = (unsigned short*)(ws + 201326592);     // ao pack   16 MiB  @192M
  unsigned short* Qf   = (unsigned short*)(ws);                 // reuse Ap1 (dead after gemm1)
  unsigned short* Kf   = (unsigned short*)(ws + 16777216);      // reuse Bp1 head
  unsigned short* Vf   = (unsigned short*)(ws + 33554432);      // reuse Bp1 +16M
  if (ws_size < 218103808) return;  // need ~208 MiB

  // Q rows of w_pack (rows < 4096) pre-scaled by (1/sqrt(128))*log2(e)
  pack_fp32<<<dim3(16, 64), 256, 0, stream>>>(hs, Ap1, HID, 0, 1.0f);
  pack_fp32<<<dim3(96, 64), 256, 0, stream>>>(wp, Bp1, HID, 4096, 0.12751744154f);
  pack_fp32<<<dim3(32, 64), 256, 0, stream>>>(wo, Bp2, HID, 0, 1.0f);

  gemm_pk<0><<<1536, 256, 0, stream>>>(Ap1, Bp1, (void*)proj, PROJN, HID);

  pack_qk<<<dim3(16, 32), 256, 0, stream>>>(proj, Qf, Kf);
  pack_v<<<dim3(16, 32), 256, 0, stream>>>(proj, Vf);

  attn_kernel<<<512, 256, 0, stream>>>(Qf, Kf, Vf, aop);

  gemm_pk<1><<<512, 256, 0, stream>>>(aop, Bp2, (void*)out, HID, HID);
}